// Round 11
// baseline (206.800 us; speedup 1.0000x reference)
//
#include <hip/hip_runtime.h>

// DCNv1 on MI355X. v10:
//  - deform GEMM: v9 structure (samples dbuf 32KB LDS, weight frags
//    global->regs prefetched) with launch_bounds (256,2) -- NOT (256,4):
//    VGPR cap 56 serialized the 16-gather pipeline (measured 99us vs 81.5).
//  - offset conv MFMA: grid 1024 (64px blocks, wave=16px) for 4 blocks/CU.
// Shapes fixed: B=4, C=64, H=W=128, Cout=64, K=3x3, stride=1, pad=1.

constexpr int B_  = 4;
constexpr int C_  = 64;
constexpr int H_  = 128;
constexpr int W_  = 128;
constexpr int CO_ = 64;
constexpr int K_  = 9;
constexpr int HW_ = H_ * W_;

typedef short bf16x8 __attribute__((ext_vector_type(8)));
typedef float f32x4  __attribute__((ext_vector_type(4)));

#define REP18(M) M(0) M(1) M(2) M(3) M(4) M(5) M(6) M(7) M(8) M(9) M(10) M(11) M(12) M(13) M(14) M(15) M(16) M(17)

// ---------------- workspace layout (float units) ----------------
constexpr size_t XT_OFF   = 0;                                   // NHWC x f32
constexpr size_t OFF_OFF  = XT_OFF + (size_t)B_ * HW_ * C_;      // offsets
constexpr size_t WDH_OFF  = OFF_OFF + (size_t)B_ * HW_ * 18;     // w_d hi bf16 [k][oc][c]
constexpr size_t WDL_OFF  = WDH_OFF + (size_t)K_ * CO_ * C_ / 2; // w_d lo
constexpr size_t WPT2_OFF = WDL_OFF + (size_t)K_ * CO_ * C_ / 2; // w_p^T [c][t][20] f32
constexpr size_t WPBH_OFF = WPT2_OFF + (size_t)C_ * K_ * 20;     // w_p mfma hi [18][32][32]
constexpr size_t WPBL_OFF = WPBH_OFF + 9216;                     // w_p mfma lo
constexpr size_t XH_OFF   = WPBL_OFF + 9216;                     // x hi bf16 NHWC
constexpr size_t XL_OFF   = XH_OFF + (size_t)B_ * HW_ * C_ / 2;  // x lo bf16
constexpr size_t WS_NEED  = (XL_OFF + (size_t)B_ * HW_ * C_ / 2) * 4;  // bytes

__device__ inline short f2bf(float x) {                 // RTN f32->bf16
    unsigned u = __float_as_uint(x);
    return (short)((u + 0x7FFF + ((u >> 16) & 1)) >> 16);
}
__device__ inline float bf2f(short s) {
    return __uint_as_float(((unsigned)(unsigned short)s) << 16);
}

// ---------------- K0a: x NCHW -> NHWC (f32 + optional bf16 hi/lo) ----------------
__global__ __launch_bounds__(256) void transpose_x_k(const float* __restrict__ x,
                                                     float* __restrict__ xt,
                                                     short* __restrict__ xh,
                                                     short* __restrict__ xl,
                                                     int wbf) {
    __shared__ float tile[64][65];
    int bid = blockIdx.x;           // 1024
    int wt  = bid & 1;
    int h   = (bid >> 1) & 127;
    int b   = bid >> 8;
    int w0  = wt * 64;
    int tid = threadIdx.x;
    int lw = tid & 63, c0 = tid >> 6;
#pragma unroll
    for (int i = 0; i < 16; ++i) {
        int c = c0 * 16 + i;
        tile[c][lw] = x[((b * C_ + c) * H_ + h) * W_ + w0 + lw];
    }
    __syncthreads();
    int lc = tid & 63, wp = tid >> 6;
#pragma unroll
    for (int i = 0; i < 16; ++i) {
        int w = wp * 16 + i;
        size_t di = ((size_t)(b * H_ + h) * W_ + w0 + w) * C_ + lc;
        float v = tile[lc][w];
        xt[di] = v;
        if (wbf) {
            short hs = (short)(__float_as_uint(v) >> 16);
            xh[di] = hs;
            xl[di] = (short)(__float_as_uint(v - bf2f(hs)) >> 16);
        }
    }
}

// ---------------- K0b: weight prep ----------------
__global__ void transpose_w_k(const float* __restrict__ wd, const float* __restrict__ wp,
                              short* __restrict__ wdh, short* __restrict__ wdl,
                              float* __restrict__ wpt2,
                              short* __restrict__ wpbh, short* __restrict__ wpbl) {
    int i = blockIdx.x * 256 + threadIdx.x;
    if (i < K_ * CO_ * C_) {               // [k][oc][c]
        int k  = i / (CO_ * C_);
        int r  = i % (CO_ * C_);
        int oc = r >> 6;
        int c  = r & 63;
        float v = wd[(oc * C_ + c) * K_ + k];
        short h = f2bf(v);
        wdh[i] = h;
        wdl[i] = f2bf(v - bf2f(h));
    }
    if (i < C_ * K_ * 20) {                // fallback path
        int j = i % 20;
        int t = (i / 20) % K_;
        int c = i / (20 * K_);
        wpt2[i] = (j < 18) ? wp[((j * C_ + c) * 3 + t / 3) * 3 + (t % 3)] : 0.f;
    }
    if (i < 18 * 32 * 32) {                // [kstep][oc(pad32)][c32]
        int kstep = i >> 10;
        int r     = i & 1023;
        int oc    = r >> 5;
        int c5    = r & 31;
        int t     = kstep >> 1;
        int c     = (kstep & 1) * 32 + c5;
        float v = (oc < 18) ? wp[((oc * C_ + c) * 3 + t / 3) * 3 + (t % 3)] : 0.f;
        short h = f2bf(v);
        wpbh[i] = h;
        wpbl[i] = f2bf(v - bf2f(h));
    }
}

// ---------------- K1a: offset conv via MFMA v2 ----------------
// Block = 64 px (4 waves x 16 px), grid = B*H*2 = 1024 -> 4 blocks/CU.
// Per kstep (t,chalf): 2 mt x 3 passes = 6 MFMA; 18 ksteps = 108 MFMA/wave.
__global__ __launch_bounds__(256) void offset_mfma_k(const short* __restrict__ xh,
                                                     const short* __restrict__ xl,
                                                     const short* __restrict__ wpbh,
                                                     const short* __restrict__ wpbl,
                                                     const float* __restrict__ bp,
                                                     float* __restrict__ off) {
    int tid  = threadIdx.x;
    int bid  = blockIdx.x;             // 1024
    int xcd  = bid & 7;                // XCD slab swizzle
    int idx  = bid >> 3;               // 0..127
    int b    = xcd >> 1;
    int h    = ((xcd & 1) << 6) | (idx >> 1);
    int w0   = (idx & 1) * 64;
    int lane = tid & 63;
    int wv   = tid >> 6;
    int l4   = lane & 15;
    int lq   = lane >> 4;
    int px   = w0 + wv * 16 + l4;      // this lane's pixel

    const short* xhb = xh + (size_t)b * HW_ * C_;
    const short* xlb = xl + (size_t)b * HW_ * C_;

    f32x4 acc0 = (f32x4){0.f, 0.f, 0.f, 0.f};
    f32x4 acc1 = (f32x4){0.f, 0.f, 0.f, 0.f};
    const bf16x8 zf = (bf16x8){0, 0, 0, 0, 0, 0, 0, 0};

#pragma unroll
    for (int t = 0; t < 9; ++t) {
        int ty = t / 3, tx = t % 3;
        int y  = h + ty - 1;
        bool yv = (y >= 0) & (y < H_);
        int yc = min(max(y, 0), H_ - 1);
        int p  = px + tx - 1;
        bool valid = yv & (p >= 0) & (p < W_);
        int pc = min(max(p, 0), W_ - 1);
        size_t rowb = ((size_t)yc * W_ + pc) * C_ + lq * 8;
#pragma unroll
        for (int chalf = 0; chalf < 2; ++chalf) {
            int kstep = t * 2 + chalf;
            const short* abase = wpbh + kstep * 1024 + l4 * 32 + lq * 8;
            const short* abasl = wpbl + kstep * 1024 + l4 * 32 + lq * 8;
            bf16x8 a0h = *(const bf16x8*)(abase);
            bf16x8 a0l = *(const bf16x8*)(abasl);
            bf16x8 a1h = *(const bf16x8*)(abase + 512);   // oc rows 16..31 (pad)
            bf16x8 a1l = *(const bf16x8*)(abasl + 512);
            size_t ai = rowb + chalf * 32;
            bf16x8 bh = *(const bf16x8*)(xhb + ai);
            bf16x8 bl = *(const bf16x8*)(xlb + ai);
            if (!valid) { bh = zf; bl = zf; }
            acc0 = __builtin_amdgcn_mfma_f32_16x16x32_bf16(a0h, bh, acc0, 0, 0, 0);
            acc0 = __builtin_amdgcn_mfma_f32_16x16x32_bf16(a0h, bl, acc0, 0, 0, 0);
            acc0 = __builtin_amdgcn_mfma_f32_16x16x32_bf16(a0l, bh, acc0, 0, 0, 0);
            acc1 = __builtin_amdgcn_mfma_f32_16x16x32_bf16(a1h, bh, acc1, 0, 0, 0);
            acc1 = __builtin_amdgcn_mfma_f32_16x16x32_bf16(a1h, bl, acc1, 0, 0, 0);
            acc1 = __builtin_amdgcn_mfma_f32_16x16x32_bf16(a1l, bh, acc1, 0, 0, 0);
        }
    }

    // D: col=l4 -> pixel, row=lq*4+r (+16 mt1) -> output channel j
    size_t obase = ((size_t)(b * H_ + h) * W_ + px) * 18;
#pragma unroll
    for (int r = 0; r < 4; ++r) {
        int j0 = lq * 4 + r;
        off[obase + j0] = acc0[r] + bp[j0];          // j0 in 0..15, always valid
        int j1 = 16 + lq * 4 + r;
        if (j1 < 18) off[obase + j1] = acc1[r] + bp[j1];
    }
}

// ---------------- K1b: offset conv VALU (fallback if ws too small) ----------------
__global__ __launch_bounds__(256) void offset_conv_k(const float* __restrict__ x,
                                                     const float* __restrict__ wpt2,
                                                     const float* __restrict__ bp,
                                                     float* __restrict__ off) {
    __shared__ float red[4][64][19];
    int tid = threadIdx.x;
    int pix = tid & 63;
    int cqu = __builtin_amdgcn_readfirstlane(tid >> 6);
    int bid = blockIdx.x;
    int w0  = (bid & 1) * 64;
    int h   = (bid >> 1) & 127;
    int b   = bid >> 8;
    int wo  = w0 + pix;

#define DECL_(i) float a##i = 0.f;
    REP18(DECL_)
#undef DECL_

    int c0 = cqu * 16;
    for (int ci = 0; ci < 16; ++ci) {
        int c = c0 + ci;
        const float* xb = x + (size_t)(b * C_ + c) * HW_;
        const float* wr = wpt2 + c * 180;
#pragma unroll
        for (int t = 0; t < 9; ++t) {
            int y  = h + t / 3 - 1;
            int xw = wo + (t % 3) - 1;
            float xv = (y >= 0 && y < H_ && xw >= 0 && xw < W_) ? xb[y * W_ + xw] : 0.f;
            const float* wrow = wr + t * 20;
#define FMA_(i) a##i = fmaf(xv, wrow[i], a##i);
            REP18(FMA_)
#undef FMA_
        }
    }
#define ST_(i) red[cqu][pix][i] = a##i;
    REP18(ST_)
#undef ST_
    __syncthreads();

    size_t base = ((size_t)(b * H_ + h) * W_ + w0) * 18;
#pragma unroll
    for (int it = 0; it < 5; ++it) {
        int idx = it * 256 + tid;
        if (idx < 64 * 18) {
            int p = idx / 18, j = idx % 18;
            float s = red[0][p][j] + red[1][p][j] + red[2][p][j] + red[3][p][j] + bp[j];
            off[base + idx] = s;
        }
    }
}

// ---------------- K2: deform sampling + bf16x3 MFMA GEMM v10 ----------------
// Samples dbuf in LDS (32KB); weight A-frags global->regs, prefetched one
// tap ahead. 1 barrier/tap. launch_bounds (256,2): DO NOT cap VGPRs harder --
// the 16 in-flight gather float4s need ~64 VGPRs (v9 at cap 4 -> 56 VGPR
// serialized the pipeline, 99us vs 81.5).
__global__ __launch_bounds__(256, 2) void deform_gemm_k(const float* __restrict__ xt,
                                                        const float* __restrict__ off,
                                                        const short* __restrict__ wdh,
                                                        const short* __restrict__ wdl,
                                                        float* __restrict__ out) {
    __shared__ __align__(16) short s_smp[2][2][64 * 64];  // [buf][hi/lo][pix][c] 32KB

    int tid = threadIdx.x;
    int bid = blockIdx.x;              // 1024
    int xcd = bid & 7;                 // XCD slab swizzle
    int idx = bid >> 3;                // 0..127
    int b   = xcd >> 1;
    int h   = ((xcd & 1) << 6) | (idx >> 1);
    int w0  = (idx & 1) * 64;

    int pix = tid & 63;
    int c0  = (tid >> 6) * 16;
    int lane = tid & 63;
    int wv   = tid >> 6;
    int l4   = lane & 15;
    int lq   = lane >> 4;
    int ocA  = wv * 16 + l4;
    int koff = lq * 8;

    f32x4 acc[4];
#pragma unroll
    for (int i = 0; i < 4; ++i) acc[i] = (f32x4){0.f, 0.f, 0.f, 0.f};

    const float* ob = off + ((size_t)(b * H_ + h) * W_ + w0 + pix) * 18;
    const float* xb = xt + (size_t)b * HW_ * C_;
    const short* wfh = wdh + ocA * 64 + koff;   // per-lane A-frag base
    const short* wfl = wdl + ocA * 64 + koff;

#define SAMP_LOAD(kk)                                                             \
    float2 o2 = *(const float2*)(ob + 2 * (kk));                                  \
    float py = o2.x + (float)(h - 1 + (kk) / 3);                                  \
    float px = o2.y + (float)(w0 + pix - 1 + (kk) % 3);                           \
    float fy = floorf(py), fx = floorf(px);                                       \
    float wy = py - fy, wx = px - fx;                                             \
    int y0 = (int)fy, x0 = (int)fx;                                               \
    int y1 = y0 + 1, x1 = x0 + 1;                                                 \
    float w00 = (1.f - wy) * (1.f - wx);                                          \
    float w01 = (1.f - wy) * wx;                                                  \
    float w10 = wy * (1.f - wx);                                                  \
    float w11 = wy * wx;                                                          \
    bool vy0 = (y0 >= 0) & (y0 < H_), vy1 = (y1 >= 0) & (y1 < H_);                \
    bool vx0 = (x0 >= 0) & (x0 < W_), vx1 = (x1 >= 0) & (x1 < W_);                \
    w00 *= (float)(vy0 & vx0);                                                    \
    w01 *= (float)(vy0 & vx1);                                                    \
    w10 *= (float)(vy1 & vx0);                                                    \
    w11 *= (float)(vy1 & vx1);                                                    \
    int cy0 = min(max(y0, 0), H_ - 1), cy1 = min(max(y1, 0), H_ - 1);             \
    int cx0 = min(max(x0, 0), W_ - 1), cx1 = min(max(x1, 0), W_ - 1);             \
    const float* r00 = xb + ((size_t)cy0 * W_ + cx0) * C_ + c0;                   \
    const float* r01 = xb + ((size_t)cy0 * W_ + cx1) * C_ + c0;                   \
    const float* r10 = xb + ((size_t)cy1 * W_ + cx0) * C_ + c0;                   \
    const float* r11 = xb + ((size_t)cy1 * W_ + cx1) * C_ + c0;                   \
    float4 qa0 = *(const float4*)(r00 + 0),  qa1 = *(const float4*)(r00 + 4);     \
    float4 qa2 = *(const float4*)(r00 + 8),  qa3 = *(const float4*)(r00 + 12);    \
    float4 qb0 = *(const float4*)(r01 + 0),  qb1 = *(const float4*)(r01 + 4);     \
    float4 qb2 = *(const float4*)(r01 + 8),  qb3 = *(const float4*)(r01 + 12);    \
    float4 qc0 = *(const float4*)(r10 + 0),  qc1 = *(const float4*)(r10 + 4);     \
    float4 qc2 = *(const float4*)(r10 + 8),  qc3 = *(const float4*)(r10 + 12);    \
    float4 qd0 = *(const float4*)(r11 + 0),  qd1 = *(const float4*)(r11 + 4);     \
    float4 qd2 = *(const float4*)(r11 + 8),  qd3 = *(const float4*)(r11 + 12);

#define SAMP_WRITE(dst)                                                           \
    {                                                                             \
        float sv[16];                                                             \
        const float4 qA[4] = {qa0, qa1, qa2, qa3};                                \
        const float4 qB[4] = {qb0, qb1, qb2, qb3};                                \
        const float4 qC[4] = {qc0, qc1, qc2, qc3};                                \
        const float4 qD[4] = {qd0, qd1, qd2, qd3};                                \
        _Pragma("unroll")                                                         \
        for (int i = 0; i < 4; ++i) {                                             \
            sv[i * 4 + 0] = w00 * qA[i].x + w01 * qB[i].x + w10 * qC[i].x + w11 * qD[i].x; \
            sv[i * 4 + 1] = w00 * qA[i].y + w01 * qB[i].y + w10 * qC[i].y + w11 * qD[i].y; \
            sv[i * 4 + 2] = w00 * qA[i].z + w01 * qB[i].z + w10 * qC[i].z + w11 * qD[i].z; \
            sv[i * 4 + 3] = w00 * qA[i].w + w01 * qB[i].w + w10 * qC[i].w + w11 * qD[i].w; \
        }                                                                         \
        _Pragma("unroll")                                                         \
        for (int i = 0; i < 2; ++i) {                                             \
            bf16x8 hv, lv;                                                        \
            _Pragma("unroll")                                                     \
            for (int j = 0; j < 8; ++j) {                                         \
                float s = sv[i * 8 + j];                                          \
                short hs = (short)(__float_as_uint(s) >> 16);                     \
                hv[j] = hs;                                                       \
                lv[j] = (short)(__float_as_uint(s - bf2f(hs)) >> 16);             \
            }                                                                     \
            int db = (pix * 128 + (c0 + i * 8) * 2) ^ ((pix & 7) << 4);           \
            *(bf16x8*)((char*)s_smp[dst][0] + db) = hv;                           \
            *(bf16x8*)((char*)s_smp[dst][1] + db) = lv;                           \
        }                                                                         \
    }

#define GEMM_TAP(cur)                                                             \
    _Pragma("unroll")                                                             \
    for (int ks = 0; ks < 2; ++ks) {                                              \
        bf16x8 ah = ks ? cw1h : cw0h;                                             \
        bf16x8 al = ks ? cw1l : cw0l;                                             \
        _Pragma("unroll")                                                         \
        for (int nt = 0; nt < 4; ++nt) {                                          \
            int prow = nt * 16 + l4;                                              \
            int bb = (prow * 128 + (ks * 32 + koff) * 2) ^ ((prow & 7) << 4);     \
            bf16x8 bh = *(const bf16x8*)((char*)s_smp[cur][0] + bb);              \
            bf16x8 bl = *(const bf16x8*)((char*)s_smp[cur][1] + bb);              \
            acc[nt] = __builtin_amdgcn_mfma_f32_16x16x32_bf16(ah, bh, acc[nt], 0, 0, 0); \
            acc[nt] = __builtin_amdgcn_mfma_f32_16x16x32_bf16(ah, bl, acc[nt], 0, 0, 0); \
            acc[nt] = __builtin_amdgcn_mfma_f32_16x16x32_bf16(al, bh, acc[nt], 0, 0, 0); \
        }                                                                         \
    }

    // prologue: tap-0 weights + samples
    bf16x8 cw0h = *(const bf16x8*)(wfh);
    bf16x8 cw1h = *(const bf16x8*)(wfh + 32);
    bf16x8 cw0l = *(const bf16x8*)(wfl);
    bf16x8 cw1l = *(const bf16x8*)(wfl + 32);
    {
        SAMP_LOAD(0)
        SAMP_WRITE(0)
    }
    __syncthreads();

#pragma unroll
    for (int k = 0; k < 9; ++k) {
        int cur = k & 1;
        if (k < 8) {
            SAMP_LOAD(k + 1)
            bf16x8 nw0h = *(const bf16x8*)(wfh + (k + 1) * 4096);
            bf16x8 nw1h = *(const bf16x8*)(wfh + (k + 1) * 4096 + 32);
            bf16x8 nw0l = *(const bf16x8*)(wfl + (k + 1) * 4096);
            bf16x8 nw1l = *(const bf16x8*)(wfl + (k + 1) * 4096 + 32);
            GEMM_TAP(cur)
            SAMP_WRITE(cur ^ 1)
            cw0h = nw0h; cw1h = nw1h; cw0l = nw0l; cw1l = nw1l;
        } else {
            GEMM_TAP(cur)
        }
        __syncthreads();
    }

    // epilogue: D col=l4 -> pixel, row=lq*4+r -> oc (within wave's 16-oc tile)
#pragma unroll
    for (int nt = 0; nt < 4; ++nt) {
#pragma unroll
        for (int r = 0; r < 4; ++r) {
            int oc = wv * 16 + lq * 4 + r;
            out[((size_t)(b * CO_ + oc) * H_ + h) * W_ + w0 + nt * 16 + l4] = acc[nt][r];
        }
    }
#undef SAMP_LOAD
#undef SAMP_WRITE
#undef GEMM_TAP
}

extern "C" void kernel_launch(void* const* d_in, const int* in_sizes, int n_in,
                              void* d_out, int out_size, void* d_ws, size_t ws_size,
                              hipStream_t stream) {
    const float* x  = (const float*)d_in[0];
    const float* wp = (const float*)d_in[1];
    const float* bp = (const float*)d_in[2];
    const float* wd = (const float*)d_in[3];
    float* out = (float*)d_out;
    float* ws  = (float*)d_ws;

    float* xt   = ws + XT_OFF;
    float* off  = ws + OFF_OFF;
    short* wdh  = (short*)(ws + WDH_OFF);
    short* wdl  = (short*)(ws + WDL_OFF);
    float* wpt2 = ws + WPT2_OFF;
    short* wpbh = (short*)(ws + WPBH_OFF);
    short* wpbl = (short*)(ws + WPBL_OFF);
    short* xh   = (short*)(ws + XH_OFF);
    short* xl   = (short*)(ws + XL_OFF);

    int big = (ws_size >= WS_NEED) ? 1 : 0;   // constant across calls -> graph-safe

    transpose_x_k<<<B_ * H_ * (W_ / 64), 256, 0, stream>>>(x, xt, xh, xl, big);
    transpose_w_k<<<(K_ * CO_ * C_ + 255) / 256, 256, 0, stream>>>(wd, wp, wdh, wdl,
                                                                   wpt2, wpbh, wpbl);
    if (big) {
        offset_mfma_k<<<B_ * H_ * 2, 256, 0, stream>>>(xh, xl, wpbh, wpbl, bp, off);
    } else {
        offset_conv_k<<<B_ * H_ * 2, 256, 0, stream>>>(x, wpt2, bp, off);
    }
    deform_gemm_k<<<B_ * HW_ / 64, 256, 0, stream>>>(xt, off, wdh, wdl, out);
}